// Round 1
// 530.705 us; speedup vs baseline: 1.2033x; 1.2033x over previous
//
#include <hip/hip_runtime.h>

// Problem: B=2, L=2048, D=2048, H=16, DH=128, M=B*L=4096
typedef unsigned short u16;
typedef _Float16 hfrag __attribute__((ext_vector_type(8)));  // 8 fp16 = 4 VGPRs
typedef float f32x4 __attribute__((ext_vector_type(4)));     // MFMA C/D frag

#define MFMA16F __builtin_amdgcn_mfma_f32_16x16x32_f16

__device__ __forceinline__ u16 f2h(float f) {
  return __builtin_bit_cast(u16, (_Float16)f);
}
__device__ __forceinline__ void splith(float x, u16 &h, u16 &l) {
  _Float16 hh = (_Float16)x;                 // RNE
  _Float16 ll = (_Float16)(x - (float)hh);   // residual, ~2^-11 rel
  h = __builtin_bit_cast(u16, hh);
  l = __builtin_bit_cast(u16, ll);
}

// async global->LDS, 16B per lane. LDS dest = wave-uniform base + lane*16.
__device__ __forceinline__ void gl2lds16(const void* g, void* l) {
  __builtin_amdgcn_global_load_lds(
      (const __attribute__((address_space(1))) unsigned int*)g,
      (__attribute__((address_space(3))) unsigned int*)l, 16, 0, 0);
}

// ---------------------------------------------------------------------------
// fp32 -> fp16 (hi plane only).
// ---------------------------------------------------------------------------
__global__ void precvt_h(const float* __restrict__ W, u16* __restrict__ hi)
{
  size_t i = ((size_t)blockIdx.x * 256 + threadIdx.x) * 4;
  float4 x = *(const float4*)(W + i);
  ushort4 h;
  h.x = f2h(x.x); h.y = f2h(x.y); h.z = f2h(x.z); h.w = f2h(x.w);
  *(ushort4*)(hi + i) = h;
}

// fp32 -> (hi, lo) fp16 planes (2-product split for Q/K-proj A operand).
__global__ void precvt_split(const float* __restrict__ X,
                             u16* __restrict__ hi, u16* __restrict__ lo)
{
  size_t i = ((size_t)blockIdx.x * 256 + threadIdx.x) * 4;
  float4 x = *(const float4*)(X + i);
  ushort4 h, l;
  splith(x.x, h.x, l.x); splith(x.y, h.y, l.y);
  splith(x.z, h.z, l.z); splith(x.w, h.w, l.w);
  *(ushort4*)(hi + i) = h;
  *(ushort4*)(lo + i) = l;
}

// ---------------------------------------------------------------------------
// Split GEMM (Q/K proj): C[4096][2048] = A @ W^T + bias, 2-product fp16
// (ah*wh + al*wh). All operands fp16 in global (pre-split/pre-cvt), staged via
// global_load_lds width=16 into XOR-swizzled LDS (block ^= row&7, BK=64 ->
// 128B rows, conflict-free ds_read_b128). No VALU staging work in K-loop.
// EMIT 0: scale by sqrt(128), emit hi+lo planes (Q).
// EMIT 1: emit hi plane only (K).
// ---------------------------------------------------------------------------
template<int EMIT>
__global__ __launch_bounds__(256, 2)
void gemm_qk(const u16* __restrict__ Ahi_g, const u16* __restrict__ Alo_g,
             const u16* __restrict__ Wh_g, const float* __restrict__ bias,
             u16* __restrict__ ohi, u16* __restrict__ olo)
{
  __shared__ u16 AhS[128 * 64];   // 16KB each, swizzled, gl2lds dest (linear)
  __shared__ u16 AlS[128 * 64];
  __shared__ u16 WS[128 * 64];

  const int tid = threadIdx.x, wave = tid >> 6, lane = tid & 63;
  const int quad = lane >> 4, l16 = lane & 15;
  const int bm = blockIdx.y * 128, bn = blockIdx.x * 128;
  const int wm = (wave >> 1) * 64, wn = (wave & 1) * 64;
  // staging: 8 rows x 8 blocks per 1KB issue; row&7 == lane>>3 (stripes of 8)
  const int srow = lane >> 3;                  // 0..7
  const int jcol = ((lane & 7) ^ srow) << 3;   // inverse-swizzled source col

  f32x4 acc[4][4] = {};

  for (int k0 = 0; k0 < 2048; k0 += 64) {
    __syncthreads();
#pragma unroll
    for (int i = 0; i < 4; ++i) {
      int r0 = wave * 32 + i * 8;
      size_t ga = (size_t)(bm + r0 + srow) * 2048 + k0 + jcol;
      size_t gw = (size_t)(bn + r0 + srow) * 2048 + k0 + jcol;
      gl2lds16(Ahi_g + ga, &AhS[r0 * 64]);
      gl2lds16(Alo_g + ga, &AlS[r0 * 64]);
      gl2lds16(Wh_g + gw, &WS[r0 * 64]);
    }
    __syncthreads();

#pragma unroll
    for (int kk = 0; kk < 2; ++kk) {
      const int jr = (((kk * 4 + quad) ^ (l16 & 7)) << 3);  // swizzled read
      hfrag ah[4], al_[4], wh[4];
#pragma unroll
      for (int i = 0; i < 4; ++i) {
        ah[i]  = *(const hfrag*)&AhS[(wm + i * 16 + l16) * 64 + jr];
        al_[i] = *(const hfrag*)&AlS[(wm + i * 16 + l16) * 64 + jr];
        wh[i]  = *(const hfrag*)&WS[(wn + i * 16 + l16) * 64 + jr];
      }
#pragma unroll
      for (int mi = 0; mi < 4; ++mi)
#pragma unroll
        for (int ni = 0; ni < 4; ++ni) {
          acc[mi][ni] = MFMA16F(ah[mi],  wh[ni], acc[mi][ni], 0, 0, 0);
          acc[mi][ni] = MFMA16F(al_[mi], wh[ni], acc[mi][ni], 0, 0, 0);
        }
    }
  }

  const float SCALE = 11.31370849898476f;   // sqrt(128) — faithful source bug
#pragma unroll
  for (int ni = 0; ni < 4; ++ni) {
    int n_g = bn + wn + ni * 16 + l16;
    float bv = bias[n_g];
#pragma unroll
    for (int mi = 0; mi < 4; ++mi)
#pragma unroll
      for (int r = 0; r < 4; ++r) {
        int m_g = bm + wm + mi * 16 + quad * 4 + r;
        float v = acc[mi][ni][r] + bv;
        int b = m_g >> 11, ll = m_g & 2047, hh = n_g >> 7, dh = n_g & 127;
        size_t off = (((size_t)(b * 16 + hh)) * 2048 + ll) * 128 + dh;
        if constexpr (EMIT == 0) {
          v *= SCALE;
          u16 h, l; splith(v, h, l);
          ohi[off] = h; olo[off] = l;
        } else {
          ohi[off] = f2h(v);
        }
      }
  }
}

// ---------------------------------------------------------------------------
// Plain fp16 GEMM, both operands fp16 global, staged via global_load_lds into
// XOR-swizzled BK=64 LDS tiles (same scheme as gemm_qk).
// OUTM 1: V-proj -> fp16 [B,H,DH,L]; computed TRANSPOSED (W rows as MFMA
//         A-operand) so stores are 32B-contiguous.  OUTM 2: fp32 [M][N].
// ---------------------------------------------------------------------------
template<int OUTM>
__global__ __launch_bounds__(256, 2)
void gemm_pl(const u16* __restrict__ A_g, const u16* __restrict__ Wh_g,
             const float* __restrict__ bias, void* __restrict__ outp)
{
  __shared__ u16 AS[128 * 64];
  __shared__ u16 WS[128 * 64];

  const int tid = threadIdx.x, wave = tid >> 6, lane = tid & 63;
  const int quad = lane >> 4, l16 = lane & 15;
  const int bm = blockIdx.y * 128, bn = blockIdx.x * 128;
  const int wm = (wave >> 1) * 64, wn = (wave & 1) * 64;
  const int srow = lane >> 3;
  const int jcol = ((lane & 7) ^ srow) << 3;

  f32x4 acc[4][4] = {};

  for (int k0 = 0; k0 < 2048; k0 += 64) {
    __syncthreads();
#pragma unroll
    for (int i = 0; i < 4; ++i) {
      int r0 = wave * 32 + i * 8;
      gl2lds16(A_g  + (size_t)(bm + r0 + srow) * 2048 + k0 + jcol, &AS[r0 * 64]);
      gl2lds16(Wh_g + (size_t)(bn + r0 + srow) * 2048 + k0 + jcol, &WS[r0 * 64]);
    }
    __syncthreads();

#pragma unroll
    for (int kk = 0; kk < 2; ++kk) {
      const int jr = (((kk * 4 + quad) ^ (l16 & 7)) << 3);
      hfrag af[4], wf[4];
#pragma unroll
      for (int i = 0; i < 4; ++i) {
        af[i] = *(const hfrag*)&AS[(wm + i * 16 + l16) * 64 + jr];
        wf[i] = *(const hfrag*)&WS[(wn + i * 16 + l16) * 64 + jr];
      }
      if constexpr (OUTM == 1) {
#pragma unroll
        for (int mi = 0; mi < 4; ++mi)
#pragma unroll
          for (int ni = 0; ni < 4; ++ni)
            acc[mi][ni] = MFMA16F(wf[mi], af[ni], acc[mi][ni], 0, 0, 0);
      } else {
#pragma unroll
        for (int mi = 0; mi < 4; ++mi)
#pragma unroll
          for (int ni = 0; ni < 4; ++ni)
            acc[mi][ni] = MFMA16F(af[mi], wf[ni], acc[mi][ni], 0, 0, 0);
      }
    }
  }

  if constexpr (OUTM == 1) {
#pragma unroll
    for (int mi = 0; mi < 4; ++mi)
#pragma unroll
      for (int r = 0; r < 4; ++r) {
        int dim = bn + wn + mi * 16 + quad * 4 + r;
        float bv = bias[dim];
        int hh = dim >> 7, dh = dim & 127;
#pragma unroll
        for (int ni = 0; ni < 4; ++ni) {
          int tok = bm + wm + ni * 16 + l16;
          int b = tok >> 11, l = tok & 2047;
          ((u16*)outp)[(((size_t)(b * 16 + hh)) * 128 + dh) * 2048 + l] =
              f2h(acc[mi][ni][r] + bv);
        }
      }
  } else {
#pragma unroll
    for (int ni = 0; ni < 4; ++ni) {
      int n_g = bn + wn + ni * 16 + l16;
      float bv = bias[n_g];
#pragma unroll
      for (int mi = 0; mi < 4; ++mi)
#pragma unroll
        for (int r = 0; r < 4; ++r) {
          int m_g = bm + wm + mi * 16 + quad * 4 + r;
          ((float*)outp)[(size_t)m_g * 2048 + n_g] = acc[mi][ni][r] + bv;
        }
    }
  }
}

// ---------------------------------------------------------------------------
// Flash attention (causal), balanced + double-buffered + XCD-swizzled.
// (unchanged this round)
// ---------------------------------------------------------------------------
__global__ __launch_bounds__(256, 1)
void attn_k(const u16* __restrict__ qhi_g, const u16* __restrict__ qlo_g,
            const u16* __restrict__ khi_g, const u16* __restrict__ vT,
            u16* __restrict__ Ow)
{
  __shared__ u16 KhiB[2][64 * 128];  // swizzle: 16B-block ^= (row & 15)
  __shared__ u16 VTB[2][128 * 64];   // swizzle: 16B-block ^= (row & 7)
  __shared__ u16 PmA[4][32][72];     // per-wave P (A-layout), +8 pad

  const int tid = threadIdx.x, wave = tid >> 6, lane = tid & 63;
  const int quad = lane >> 4, l16 = lane & 15;
  const int bh = blockIdx.x & 31, qx = blockIdx.x >> 5;
  const u16* Qhb = qhi_g + (size_t)bh * 2048 * 128;
  const u16* Qlb = qlo_g + (size_t)bh * 2048 * 128;
  const u16* Khb = khi_g + (size_t)bh * 2048 * 128;
  const u16* Vb  = vT    + (size_t)bh * 128 * 2048;

  const int krl = lane >> 4, kpb = lane & 15;   // K staging: 4 rows x 16 blocks
  const int vrl = lane >> 3, vpb = lane & 7;    // V staging: 8 rows x 8 blocks

  hfrag ones;
#pragma unroll
  for (int j = 0; j < 8; ++j) ones[j] = (_Float16)1.0f;

  auto stage = [&](int kv0, int bsel) {
#pragma unroll
    for (int i = 0; i < 4; ++i) {
      int r = wave * 16 + i * 4 + krl;
      int j = kpb ^ (r & 15);
      gl2lds16(Khb + (size_t)(kv0 + r) * 128 + j * 8,
               &KhiB[bsel][(wave * 16 + i * 4) * 128]);
      int rv = wave * 32 + i * 8 + vrl;
      int jv = vpb ^ (rv & 7);
      gl2lds16(Vb + (size_t)rv * 2048 + kv0 + jv * 8,
               &VTB[bsel][(wave * 32 + i * 8) * 64]);
    }
  };

  const int b = bh >> 4, h = bh & 15;

#pragma unroll 1
  for (int ph = 0; ph < 2; ++ph) {
    const int qt = (ph == 0) ? qx : 15 - qx;
    const int qrow0 = qt * 128 + wave * 32;
    const int nkv = 2 * (qt + 1);   // always even -> last tile uses buf 1

    stage(0, 0);                    // buf0 free: prev phase ended on buf1

    // Q fragments (B-operand layout == contiguous rows), resident
    hfrag qhf[2][4], qlf[2][4];
#pragma unroll
    for (int t = 0; t < 2; ++t)
#pragma unroll
      for (int f = 0; f < 4; ++f) {
        size_t off = (size_t)(qrow0 + t * 16 + l16) * 128 + f * 32 + quad * 8;
        qhf[t][f] = *(const hfrag*)(Qhb + off);
        qlf[t][f] = *(const hfrag*)(Qlb + off);
      }

    float mprev[2] = {-3e38f, -3e38f};
    f32x4 o[2][9] = {};             // d=8: ones column (softmax denom)

#pragma unroll 1
    for (int kt = 0; kt < nkv; ++kt) {
      const int kv0 = kt * 64, bsel = kt & 1;
      __syncthreads();                          // drains tile-kt loads
      if (kt + 1 < nkv) stage((kt + 1) * 64, 1 - bsel);  // a full iter in flight

      if (kv0 <= qrow0 + 31) {                  // wave-uniform: any unmasked row?
        // S^T = K Q^T  (2-product fp16: k*qh + k*ql)
        f32x4 st[4][2] = {};
#pragma unroll
        for (int f = 0; f < 4; ++f)
#pragma unroll
          for (int c = 0; c < 4; ++c) {
            int poff = (c * 16 + l16) * 128 + (((f * 4 + quad) ^ l16) << 3);
            hfrag kf = *(const hfrag*)&KhiB[bsel][poff];
#pragma unroll
            for (int t = 0; t < 2; ++t) {
              st[c][t] = MFMA16F(kf, qhf[t][f], st[c][t], 0, 0, 0);
              st[c][t] = MFMA16F(kf, qlf[t][f], st[c][t], 0, 0, 0);
            }
          }

        // softmax: row = t*16+l16 (lane dim), kv = c*16+quad*4+r
        const bool needmask = (kv0 + 64 > qrow0);
        float al2[2];
#pragma unroll
        for (int t = 0; t < 2; ++t) {
          const int rg = qrow0 + t * 16 + l16;
          if (needmask) {
#pragma unroll
            for (int c = 0; c < 4; ++c)
#pragma unroll
              for (int r = 0; r < 4; ++r)
                if (kv0 + c * 16 + quad * 4 + r > rg) st[c][t][r] = -1e7f;
          }
          float mx = st[0][t][0];
#pragma unroll
          for (int c = 0; c < 4; ++c)
#pragma unroll
            for (int r = 0; r < 4; ++r) mx = fmaxf(mx, st[c][t][r]);
          mx = fmaxf(mx, __shfl_xor(mx, 16));
          mx = fmaxf(mx, __shfl_xor(mx, 32));
          float mnew = fmaxf(mprev[t], mx);
          al2[t] = __expf(mprev[t] - mnew);
          mprev[t] = mnew;
#pragma unroll
          for (int c = 0; c < 4; ++c) {
            ushort4 pk;
            pk.x = f2h(__expf(st[c][t][0] - mnew));
            pk.y = f2h(__expf(st[c][t][1] - mnew));
            pk.z = f2h(__expf(st[c][t][2] - mnew));
            pk.w = f2h(__expf(st[c][t][3] - mnew));
            *(ushort4*)&PmA[wave][t * 16 + l16][c * 16 + quad * 4] = pk;
          }
        }
        // rescale O only when some row's max moved (wave-uniform gate)
        if (__ballot(al2[0] != 1.f || al2[1] != 1.f)) {
#pragma unroll
          for (int t = 0; t < 2; ++t) {
            f32x4 av;
            av[0] = __shfl(al2[t], quad * 4 + 0);
            av[1] = __shfl(al2[t], quad * 4 + 1);
            av[2] = __shfl(al2[t], quad * 4 + 2);
            av[3] = __shfl(al2[t], quad * 4 + 3);
#pragma unroll
            for (int d = 0; d < 9; ++d) o[t][d] *= av;
          }
        }

        // O += P V   (P from per-wave LDS in A-layout; d=8 accumulates denom)
#pragma unroll
        for (int k2 = 0; k2 < 2; ++k2) {
          hfrag pf0 = *(const hfrag*)&PmA[wave][l16][k2 * 32 + quad * 8];
          hfrag pf1 = *(const hfrag*)&PmA[wave][16 + l16][k2 * 32 + quad * 8];
#pragma unroll
          for (int d = 0; d < 9; ++d) {
            hfrag vf = (d < 8)
                ? *(const hfrag*)&VTB[bsel][(d * 16 + l16) * 64 +
                                            (((k2 * 4 + quad) ^ (l16 & 7)) << 3)]
                : ones;
            o[0][d] = MFMA16F(pf0, vf, o[0][d], 0, 0, 0);
            o[1][d] = MFMA16F(pf1, vf, o[1][d], 0, 0, 0);
          }
        }
      }
    }

    // epilogue: normalize by the ones column, store fp16 to Ow[B,L,D]
#pragma unroll
    for (int t = 0; t < 2; ++t)
#pragma unroll
      for (int r = 0; r < 4; ++r) {
        int rg = qrow0 + t * 16 + quad * 4 + r;
        float inv = 1.f / o[t][8][r];
#pragma unroll
        for (int d = 0; d < 8; ++d)
          Ow[((size_t)(b * 2048 + rg)) * 2048 + h * 128 + d * 16 + l16] =
              f2h(o[t][d][r] * inv);
      }
  }
}

// ---------------------------------------------------------------------------
extern "C" void kernel_launch(void* const* d_in, const int* in_sizes, int n_in,
                              void* d_out, int out_size, void* d_ws, size_t ws_size,
                              hipStream_t stream) {
  const float* q  = (const float*)d_in[0];
  const float* k  = (const float*)d_in[1];
  const float* v  = (const float*)d_in[2];
  const float* Wq = (const float*)d_in[3];
  const float* bq = (const float*)d_in[4];
  const float* Wk = (const float*)d_in[5];
  const float* bk = (const float*)d_in[6];
  const float* Wv = (const float*)d_in[7];
  const float* bv = (const float*)d_in[8];
  const float* Wo = (const float*)d_in[9];
  const float* bo = (const float*)d_in[10];

  // Workspace (u16 units), 92.27 MB total (same footprint as before):
  //   qHi qLo kHi : 3 x 16.78 MB persistent fp16 planes
  //   WH (8.39MB) : WqH -> WkH -> WvH -> WoH (sequential reuse)
  //   bufA        : qAhi -> kAhi -> vH -> Ow   (16.78 MB, sequential reuse)
  //   bufB        : qAlo -> kAlo -> vT         (16.78 MB, sequential reuse)
  u16* ws   = (u16*)d_ws;
  u16* qHi  = ws;
  u16* qLo  = ws + 8388608u;
  u16* kHi  = ws + 16777216u;
  u16* WH   = ws + 25165824u;      // 4.19M u16 = 8.39 MB
  u16* bufA = ws + 29360128u;
  u16* bufB = ws + 37748736u;

  dim3 blk(256);
  dim3 gg(16, 32);   // N/128, M/128

  // Q projection
  precvt_split<<<8192, blk, 0, stream>>>(q, bufA, bufB);
  precvt_h<<<4096, blk, 0, stream>>>(Wq, WH);
  gemm_qk<0><<<gg, blk, 0, stream>>>(bufA, bufB, WH, bq, qHi, qLo);
  // K projection
  precvt_split<<<8192, blk, 0, stream>>>(k, bufA, bufB);
  precvt_h<<<4096, blk, 0, stream>>>(Wk, WH);
  gemm_qk<1><<<gg, blk, 0, stream>>>(bufA, bufB, WH, bk, kHi, nullptr);
  // V projection (transposed out -> bufB)
  precvt_h<<<8192, blk, 0, stream>>>(v, bufA);
  precvt_h<<<4096, blk, 0, stream>>>(Wv, WH);
  gemm_pl<1><<<gg, blk, 0, stream>>>(bufA, WH, bv, bufB);
  // Attention (Ow -> bufA; vH in bufA is dead by the time attn writes)
  attn_k<<<dim3(256), blk, 0, stream>>>(qHi, qLo, kHi, bufB, bufA);
  // Output projection
  precvt_h<<<4096, blk, 0, stream>>>(Wo, WH);
  gemm_pl<2><<<gg, blk, 0, stream>>>(bufA, WH, bo, d_out);
}

// Round 3
// 518.735 us; speedup vs baseline: 1.2311x; 1.0231x over previous
//
#include <hip/hip_runtime.h>

// Problem: B=2, L=2048, D=2048, H=16, DH=128, M=B*L=4096
typedef unsigned short u16;
typedef _Float16 hfrag __attribute__((ext_vector_type(8)));  // 8 fp16 = 4 VGPRs
typedef float f32x4 __attribute__((ext_vector_type(4)));     // MFMA C/D frag

#define MFMA16F __builtin_amdgcn_mfma_f32_16x16x32_f16

__device__ __forceinline__ u16 f2h(float f) {
  return __builtin_bit_cast(u16, (_Float16)f);
}
__device__ __forceinline__ void splith(float x, u16 &h, u16 &l) {
  _Float16 hh = (_Float16)x;                 // RNE
  _Float16 ll = (_Float16)(x - (float)hh);   // residual, ~2^-11 rel
  h = __builtin_bit_cast(u16, hh);
  l = __builtin_bit_cast(u16, ll);
}
// packed f32x2 -> fp16x2 (RTZ), as raw u32
__device__ __forceinline__ unsigned int pkrtz(float a, float b) {
  return __builtin_bit_cast(unsigned int, __builtin_amdgcn_cvt_pkrtz(a, b));
}

// async global->LDS, 16B per lane. LDS dest = wave-uniform base + lane*16.
__device__ __forceinline__ void gl2lds16(const void* g, void* l) {
  __builtin_amdgcn_global_load_lds(
      (const __attribute__((address_space(1))) unsigned int*)g,
      (__attribute__((address_space(3))) unsigned int*)l, 16, 0, 0);
}

// ---------------------------------------------------------------------------
// fp32 -> fp16 (hi plane only).
// ---------------------------------------------------------------------------
__global__ void precvt_h(const float* __restrict__ W, u16* __restrict__ hi)
{
  size_t i = ((size_t)blockIdx.x * 256 + threadIdx.x) * 4;
  float4 x = *(const float4*)(W + i);
  ushort4 h;
  h.x = f2h(x.x); h.y = f2h(x.y); h.z = f2h(x.z); h.w = f2h(x.w);
  *(ushort4*)(hi + i) = h;
}

// fp32 -> (hi, lo) fp16 planes (2-product split for Q/K-proj A operand).
__global__ void precvt_split(const float* __restrict__ X,
                             u16* __restrict__ hi, u16* __restrict__ lo)
{
  size_t i = ((size_t)blockIdx.x * 256 + threadIdx.x) * 4;
  float4 x = *(const float4*)(X + i);
  ushort4 h, l;
  splith(x.x, h.x, l.x); splith(x.y, h.y, l.y);
  splith(x.z, h.z, l.z); splith(x.w, h.w, l.w);
  *(ushort4*)(hi + i) = h;
  *(ushort4*)(lo + i) = l;
}

// ---------------------------------------------------------------------------
// Split GEMM (Q/K proj): C[4096][2048] = A @ W^T + bias, 2-product fp16
// (ah*wh + al*wh). All operands fp16 in global (pre-split/pre-cvt), staged via
// global_load_lds width=16 into XOR-swizzled LDS (block ^= row&7, BK=64 ->
// 128B rows, conflict-free ds_read_b128). No VALU staging work in K-loop.
// EMIT 0: scale by sqrt(128)*log2(e), emit hi+lo planes (Q; attn uses exp2).
// EMIT 1: emit hi plane only (K).
// ---------------------------------------------------------------------------
template<int EMIT>
__global__ __launch_bounds__(256, 2)
void gemm_qk(const u16* __restrict__ Ahi_g, const u16* __restrict__ Alo_g,
             const u16* __restrict__ Wh_g, const float* __restrict__ bias,
             u16* __restrict__ ohi, u16* __restrict__ olo)
{
  __shared__ u16 AhS[128 * 64];   // 16KB each, swizzled, gl2lds dest (linear)
  __shared__ u16 AlS[128 * 64];
  __shared__ u16 WS[128 * 64];

  const int tid = threadIdx.x, wave = tid >> 6, lane = tid & 63;
  const int quad = lane >> 4, l16 = lane & 15;
  const int bm = blockIdx.y * 128, bn = blockIdx.x * 128;
  const int wm = (wave >> 1) * 64, wn = (wave & 1) * 64;
  // staging: 8 rows x 8 blocks per 1KB issue; row&7 == lane>>3 (stripes of 8)
  const int srow = lane >> 3;                  // 0..7
  const int jcol = ((lane & 7) ^ srow) << 3;   // inverse-swizzled source col

  f32x4 acc[4][4] = {};

  for (int k0 = 0; k0 < 2048; k0 += 64) {
    __syncthreads();
#pragma unroll
    for (int i = 0; i < 4; ++i) {
      int r0 = wave * 32 + i * 8;
      size_t ga = (size_t)(bm + r0 + srow) * 2048 + k0 + jcol;
      size_t gw = (size_t)(bn + r0 + srow) * 2048 + k0 + jcol;
      gl2lds16(Ahi_g + ga, &AhS[r0 * 64]);
      gl2lds16(Alo_g + ga, &AlS[r0 * 64]);
      gl2lds16(Wh_g + gw, &WS[r0 * 64]);
    }
    __syncthreads();

#pragma unroll
    for (int kk = 0; kk < 2; ++kk) {
      const int jr = (((kk * 4 + quad) ^ (l16 & 7)) << 3);  // swizzled read
      hfrag ah[4], al_[4], wh[4];
#pragma unroll
      for (int i = 0; i < 4; ++i) {
        ah[i]  = *(const hfrag*)&AhS[(wm + i * 16 + l16) * 64 + jr];
        al_[i] = *(const hfrag*)&AlS[(wm + i * 16 + l16) * 64 + jr];
        wh[i]  = *(const hfrag*)&WS[(wn + i * 16 + l16) * 64 + jr];
      }
#pragma unroll
      for (int mi = 0; mi < 4; ++mi)
#pragma unroll
        for (int ni = 0; ni < 4; ++ni) {
          acc[mi][ni] = MFMA16F(ah[mi],  wh[ni], acc[mi][ni], 0, 0, 0);
          acc[mi][ni] = MFMA16F(al_[mi], wh[ni], acc[mi][ni], 0, 0, 0);
        }
    }
  }

  // sqrt(128) [faithful source bug] * log2(e) [attn computes exp2]
  const float SCALE = 16.3222311f;
#pragma unroll
  for (int ni = 0; ni < 4; ++ni) {
    int n_g = bn + wn + ni * 16 + l16;
    float bv = bias[n_g];
#pragma unroll
    for (int mi = 0; mi < 4; ++mi)
#pragma unroll
      for (int r = 0; r < 4; ++r) {
        int m_g = bm + wm + mi * 16 + quad * 4 + r;
        float v = acc[mi][ni][r] + bv;
        int b = m_g >> 11, ll = m_g & 2047, hh = n_g >> 7, dh = n_g & 127;
        size_t off = (((size_t)(b * 16 + hh)) * 2048 + ll) * 128 + dh;
        if constexpr (EMIT == 0) {
          v *= SCALE;
          u16 h, l; splith(v, h, l);
          ohi[off] = h; olo[off] = l;
        } else {
          ohi[off] = f2h(v);
        }
      }
  }
}

// ---------------------------------------------------------------------------
// Plain fp16 GEMM, both operands fp16 global, staged via global_load_lds into
// XOR-swizzled BK=64 LDS tiles (same scheme as gemm_qk).
// OUTM 1: V-proj -> fp16 [B,H,DH,L]; computed TRANSPOSED (W rows as MFMA
//         A-operand) so stores are 32B-contiguous.  OUTM 2: fp32 [M][N].
// ---------------------------------------------------------------------------
template<int OUTM>
__global__ __launch_bounds__(256, 2)
void gemm_pl(const u16* __restrict__ A_g, const u16* __restrict__ Wh_g,
             const float* __restrict__ bias, void* __restrict__ outp)
{
  __shared__ u16 AS[128 * 64];
  __shared__ u16 WS[128 * 64];

  const int tid = threadIdx.x, wave = tid >> 6, lane = tid & 63;
  const int quad = lane >> 4, l16 = lane & 15;
  const int bm = blockIdx.y * 128, bn = blockIdx.x * 128;
  const int wm = (wave >> 1) * 64, wn = (wave & 1) * 64;
  const int srow = lane >> 3;
  const int jcol = ((lane & 7) ^ srow) << 3;

  f32x4 acc[4][4] = {};

  for (int k0 = 0; k0 < 2048; k0 += 64) {
    __syncthreads();
#pragma unroll
    for (int i = 0; i < 4; ++i) {
      int r0 = wave * 32 + i * 8;
      gl2lds16(A_g  + (size_t)(bm + r0 + srow) * 2048 + k0 + jcol, &AS[r0 * 64]);
      gl2lds16(Wh_g + (size_t)(bn + r0 + srow) * 2048 + k0 + jcol, &WS[r0 * 64]);
    }
    __syncthreads();

#pragma unroll
    for (int kk = 0; kk < 2; ++kk) {
      const int jr = (((kk * 4 + quad) ^ (l16 & 7)) << 3);
      hfrag af[4], wf[4];
#pragma unroll
      for (int i = 0; i < 4; ++i) {
        af[i] = *(const hfrag*)&AS[(wm + i * 16 + l16) * 64 + jr];
        wf[i] = *(const hfrag*)&WS[(wn + i * 16 + l16) * 64 + jr];
      }
      if constexpr (OUTM == 1) {
#pragma unroll
        for (int mi = 0; mi < 4; ++mi)
#pragma unroll
          for (int ni = 0; ni < 4; ++ni)
            acc[mi][ni] = MFMA16F(wf[mi], af[ni], acc[mi][ni], 0, 0, 0);
      } else {
#pragma unroll
        for (int mi = 0; mi < 4; ++mi)
#pragma unroll
          for (int ni = 0; ni < 4; ++ni)
            acc[mi][ni] = MFMA16F(af[mi], wf[ni], acc[mi][ni], 0, 0, 0);
      }
    }
  }

  if constexpr (OUTM == 1) {
#pragma unroll
    for (int mi = 0; mi < 4; ++mi)
#pragma unroll
      for (int r = 0; r < 4; ++r) {
        int dim = bn + wn + mi * 16 + quad * 4 + r;
        float bv = bias[dim];
        int hh = dim >> 7, dh = dim & 127;
#pragma unroll
        for (int ni = 0; ni < 4; ++ni) {
          int tok = bm + wm + ni * 16 + l16;
          int b = tok >> 11, l = tok & 2047;
          ((u16*)outp)[(((size_t)(b * 16 + hh)) * 128 + dh) * 2048 + l] =
              f2h(acc[mi][ni][r] + bv);
        }
      }
  } else {
#pragma unroll
    for (int ni = 0; ni < 4; ++ni) {
      int n_g = bn + wn + ni * 16 + l16;
      float bv = bias[n_g];
#pragma unroll
      for (int mi = 0; mi < 4; ++mi)
#pragma unroll
        for (int r = 0; r < 4; ++r) {
          int m_g = bm + wm + mi * 16 + quad * 4 + r;
          ((float*)outp)[(size_t)m_g * 2048 + n_g] = acc[mi][ni][r] + bv;
        }
    }
  }
}

// ---------------------------------------------------------------------------
// Flash attention (causal), 2-blocks/CU co-resident for MFMA||VALU overlap.
// Grid 512: bh = bid & 31 (same head -> same XCD for K/V L2 locality),
// xi = bid >> 5; qt = xi<8 ? xi : 23-xi so co-resident pair (bid, bid+256)
// handles q-tiles (a, 15-a) -> ~uniform 17 KV-tile units per CU.
// LDS = exactly 80KB (Khi 32K dbuf + VT 32K dbuf + PmA 16K swizzled) so two
// blocks fit in the 160KB CU budget; launch_bounds(256,2).
// Scores arrive pre-scaled by log2(e): softmax uses bare v_exp_f32 (exp2f)
// and packs P via v_cvt_pkrtz.
// ---------------------------------------------------------------------------
__global__ __launch_bounds__(256, 2)
void attn_k(const u16* __restrict__ qhi_g, const u16* __restrict__ qlo_g,
            const u16* __restrict__ khi_g, const u16* __restrict__ vT,
            u16* __restrict__ Ow)
{
  __shared__ u16 KhiB[2][64 * 128];  // swizzle: 16B-block ^= (row & 15)
  __shared__ u16 VTB[2][128 * 64];   // swizzle: 16B-block ^= (row & 7)
  __shared__ u16 PmA[4][32][64];     // per-wave P; 16B-block ^= (row & 7)

  const int tid = threadIdx.x, wave = tid >> 6, lane = tid & 63;
  const int quad = lane >> 4, l16 = lane & 15;
  const int bh = blockIdx.x & 31;
  const int xi = blockIdx.x >> 5;               // 0..15
  const int qt = (xi < 8) ? xi : 23 - xi;       // pair (xi, xi+8) -> (a, 15-a)
  const u16* Qhb = qhi_g + (size_t)bh * 2048 * 128;
  const u16* Qlb = qlo_g + (size_t)bh * 2048 * 128;
  const u16* Khb = khi_g + (size_t)bh * 2048 * 128;
  const u16* Vb  = vT    + (size_t)bh * 128 * 2048;

  const int krl = lane >> 4, kpb = lane & 15;   // K staging: 4 rows x 16 blocks
  const int vrl = lane >> 3, vpb = lane & 7;    // V staging: 8 rows x 8 blocks

  u16* Pw = &PmA[wave][0][0];

  hfrag ones;
#pragma unroll
  for (int j = 0; j < 8; ++j) ones[j] = (_Float16)1.0f;

  auto stage = [&](int kv0, int bsel) {
#pragma unroll
    for (int i = 0; i < 4; ++i) {
      int r = wave * 16 + i * 4 + krl;
      int j = kpb ^ (r & 15);
      gl2lds16(Khb + (size_t)(kv0 + r) * 128 + j * 8,
               &KhiB[bsel][(wave * 16 + i * 4) * 128]);
      int rv = wave * 32 + i * 8 + vrl;
      int jv = vpb ^ (rv & 7);
      gl2lds16(Vb + (size_t)rv * 2048 + kv0 + jv * 8,
               &VTB[bsel][(wave * 32 + i * 8) * 64]);
    }
  };

  const int b = bh >> 4, h = bh & 15;
  const int qrow0 = qt * 128 + wave * 32;
  const int nkv = 2 * (qt + 1);

  stage(0, 0);

  // Q fragments (B-operand layout == contiguous rows), resident
  hfrag qhf[2][4], qlf[2][4];
#pragma unroll
  for (int t = 0; t < 2; ++t)
#pragma unroll
    for (int f = 0; f < 4; ++f) {
      size_t off = (size_t)(qrow0 + t * 16 + l16) * 128 + f * 32 + quad * 8;
      qhf[t][f] = *(const hfrag*)(Qhb + off);
      qlf[t][f] = *(const hfrag*)(Qlb + off);
    }

  float mprev[2] = {-3e38f, -3e38f};
  f32x4 o[2][9] = {};             // d=8: ones column (softmax denom)

#pragma unroll 1
  for (int kt = 0; kt < nkv; ++kt) {
    const int kv0 = kt * 64, bsel = kt & 1;
    __syncthreads();                          // drains tile-kt loads
    if (kt + 1 < nkv) stage((kt + 1) * 64, 1 - bsel);  // a full iter in flight

    if (kv0 <= qrow0 + 31) {                  // wave-uniform: any unmasked row?
      // S^T = K Q^T  (2-product fp16: k*qh + k*ql); S pre-scaled by log2(e)
      f32x4 st[4][2] = {};
#pragma unroll
      for (int f = 0; f < 4; ++f)
#pragma unroll
        for (int c = 0; c < 4; ++c) {
          int poff = (c * 16 + l16) * 128 + (((f * 4 + quad) ^ l16) << 3);
          hfrag kf = *(const hfrag*)&KhiB[bsel][poff];
#pragma unroll
          for (int t = 0; t < 2; ++t) {
            st[c][t] = MFMA16F(kf, qhf[t][f], st[c][t], 0, 0, 0);
            st[c][t] = MFMA16F(kf, qlf[t][f], st[c][t], 0, 0, 0);
          }
        }

      // softmax: row = t*16+l16 (lane dim), kv = c*16+quad*4+r
      const bool needmask = (kv0 + 64 > qrow0);
      float al2[2];
#pragma unroll
      for (int t = 0; t < 2; ++t) {
        const int rg = qrow0 + t * 16 + l16;
        if (needmask) {
#pragma unroll
          for (int c = 0; c < 4; ++c)
#pragma unroll
            for (int r = 0; r < 4; ++r)
              if (kv0 + c * 16 + quad * 4 + r > rg) st[c][t][r] = -1e7f;
        }
        float mx = st[0][t][0];
#pragma unroll
        for (int c = 0; c < 4; ++c)
#pragma unroll
          for (int r = 0; r < 4; ++r) mx = fmaxf(mx, st[c][t][r]);
        mx = fmaxf(mx, __shfl_xor(mx, 16));
        mx = fmaxf(mx, __shfl_xor(mx, 32));
        float mnew = fmaxf(mprev[t], mx);
        al2[t] = exp2f(mprev[t] - mnew);
        mprev[t] = mnew;
        const int rr = t * 16 + l16;
#pragma unroll
        for (int c = 0; c < 4; ++c) {
          uint2 pk;
          pk.x = pkrtz(exp2f(st[c][t][0] - mnew), exp2f(st[c][t][1] - mnew));
          pk.y = pkrtz(exp2f(st[c][t][2] - mnew), exp2f(st[c][t][3] - mnew));
          int b16 = (2 * c + (quad >> 1)) ^ (l16 & 7);
          *(uint2*)&Pw[rr * 64 + b16 * 8 + (quad & 1) * 4] = pk;
        }
      }
      // rescale O only when some row's max moved (wave-uniform gate)
      if (__ballot(al2[0] != 1.f || al2[1] != 1.f)) {
#pragma unroll
        for (int t = 0; t < 2; ++t) {
          f32x4 av;
          av[0] = __shfl(al2[t], quad * 4 + 0);
          av[1] = __shfl(al2[t], quad * 4 + 1);
          av[2] = __shfl(al2[t], quad * 4 + 2);
          av[3] = __shfl(al2[t], quad * 4 + 3);
#pragma unroll
          for (int d = 0; d < 9; ++d) o[t][d] *= av;
        }
      }

      // O += P V   (P from per-wave LDS in A-layout; d=8 accumulates denom)
#pragma unroll
      for (int k2 = 0; k2 < 2; ++k2) {
        const int bs = ((k2 * 4 + quad) ^ (l16 & 7)) << 3;
        hfrag pf0 = *(const hfrag*)&Pw[l16 * 64 + bs];
        hfrag pf1 = *(const hfrag*)&Pw[(16 + l16) * 64 + bs];
#pragma unroll
        for (int d = 0; d < 9; ++d) {
          hfrag vf = (d < 8)
              ? *(const hfrag*)&VTB[bsel][(d * 16 + l16) * 64 +
                                          (((k2 * 4 + quad) ^ (l16 & 7)) << 3)]
              : ones;
          o[0][d] = MFMA16F(pf0, vf, o[0][d], 0, 0, 0);
          o[1][d] = MFMA16F(pf1, vf, o[1][d], 0, 0, 0);
        }
      }
    }
  }

  // epilogue: normalize by the ones column, store fp16 to Ow[B,L,D]
#pragma unroll
  for (int t = 0; t < 2; ++t)
#pragma unroll
    for (int r = 0; r < 4; ++r) {
      int rg = qrow0 + t * 16 + quad * 4 + r;
      float inv = 1.f / o[t][8][r];
#pragma unroll
      for (int d = 0; d < 8; ++d)
        Ow[((size_t)(b * 2048 + rg)) * 2048 + h * 128 + d * 16 + l16] =
            f2h(o[t][d][r] * inv);
    }
}

// ---------------------------------------------------------------------------
extern "C" void kernel_launch(void* const* d_in, const int* in_sizes, int n_in,
                              void* d_out, int out_size, void* d_ws, size_t ws_size,
                              hipStream_t stream) {
  const float* q  = (const float*)d_in[0];
  const float* k  = (const float*)d_in[1];
  const float* v  = (const float*)d_in[2];
  const float* Wq = (const float*)d_in[3];
  const float* bq = (const float*)d_in[4];
  const float* Wk = (const float*)d_in[5];
  const float* bk = (const float*)d_in[6];
  const float* Wv = (const float*)d_in[7];
  const float* bv = (const float*)d_in[8];
  const float* Wo = (const float*)d_in[9];
  const float* bo = (const float*)d_in[10];

  // Workspace (u16 units), 92.27 MB total:
  //   qHi qLo kHi : 3 x 16.78 MB persistent fp16 planes
  //   WH (8.39MB) : WqH -> WkH -> WvH -> WoH (sequential reuse)
  //   bufA        : qAhi -> kAhi -> vH -> Ow   (16.78 MB, sequential reuse)
  //   bufB        : qAlo -> kAlo -> vT         (16.78 MB, sequential reuse)
  u16* ws   = (u16*)d_ws;
  u16* qHi  = ws;
  u16* qLo  = ws + 8388608u;
  u16* kHi  = ws + 16777216u;
  u16* WH   = ws + 25165824u;      // 4.19M u16 = 8.39 MB
  u16* bufA = ws + 29360128u;
  u16* bufB = ws + 37748736u;

  dim3 blk(256);
  dim3 gg(16, 32);   // N/128, M/128

  // Q projection
  precvt_split<<<8192, blk, 0, stream>>>(q, bufA, bufB);
  precvt_h<<<4096, blk, 0, stream>>>(Wq, WH);
  gemm_qk<0><<<gg, blk, 0, stream>>>(bufA, bufB, WH, bq, qHi, qLo);
  // K projection
  precvt_split<<<8192, blk, 0, stream>>>(k, bufA, bufB);
  precvt_h<<<4096, blk, 0, stream>>>(Wk, WH);
  gemm_qk<1><<<gg, blk, 0, stream>>>(bufA, bufB, WH, bk, kHi, nullptr);
  // V projection (transposed out -> bufB)
  precvt_h<<<8192, blk, 0, stream>>>(v, bufA);
  precvt_h<<<4096, blk, 0, stream>>>(Wv, WH);
  gemm_pl<1><<<gg, blk, 0, stream>>>(bufA, WH, bv, bufB);
  // Attention (Ow -> bufA; vH in bufA is dead by the time attn writes)
  attn_k<<<dim3(512), blk, 0, stream>>>(qHi, qLo, kHi, bufB, bufA);
  // Output projection
  precvt_h<<<4096, blk, 0, stream>>>(Wo, WH);
  gemm_pl<2><<<gg, blk, 0, stream>>>(bufA, WH, bo, d_out);
}